// Round 5
// baseline (137.274 us; speedup 1.0000x reference)
//
#include <hip/hip_runtime.h>
#include <hip/hip_cooperative_groups.h>

namespace cg = cooperative_groups;

#define HID 128
#define NN  256
#define BB  8
#define NCATS 64

// ---------------------------------------------------------------------------
// bf16 pack/unpack (RNE rounding on pack)
__device__ inline unsigned pack_bf16(float lo, float hi) {
    unsigned ul = __float_as_uint(lo);
    unsigned uh = __float_as_uint(hi);
    ul = (ul + 0x7fffu + ((ul >> 16) & 1u)) >> 16;
    uh = (uh + 0x7fffu + ((uh >> 16) & 1u)) & 0xffff0000u;
    return ul | uh;
}
__device__ inline float bf_lo(unsigned v) { return __uint_as_float(v << 16); }
__device__ inline float bf_hi(unsigned v) { return __uint_as_float(v & 0xffff0000u); }

// Wave-per-row LN reduction (row split as a=dim[lane], c=dim[lane+64]).
__device__ inline void ln_stats(float a, float c, float& mean, float& rs) {
    float s = a + c;
    float q = a * a + c * c;
    #pragma unroll
    for (int m = 32; m; m >>= 1) {
        s += __shfl_xor(s, m);
        q += __shfl_xor(q, m);
    }
    mean = s * (1.0f / 128.0f);
    float var = q * (1.0f / 128.0f) - mean * mean;
    rs = rsqrtf(var + 1e-5f);
}

struct KArgs {
    const float* x; const float* emb;
    const float* inW1; const float* inb1; const float* ing1; const float* inbt1;
    const float* inW2; const float* inb2; const float* ing2; const float* inbt2;
    const float* cW1; const float* cb1; const float* cg1; const float* cbt1;
    const float* cW2; const float* cb2; const float* cg2; const float* cbt2;
    const float* ceps; const float* lng; const float* lnb;
    const float* outW; const float* outb;
    const int* ecat;
    float* hA; float* hB; float* dout;
};

// ---------------------------------------------------------------------------
// Fused kernel. Block (b, jg) owns dst rows jg*8..jg*8+7 of item b.
// grid = 256 blocks x 512 threads, 1 block/CU -> cooperative launch always fits.
// lbeg<0: run input-MLP phase. Layers [max(lbeg,0), lend). dosync: grid.sync
// between phases (cooperative mode only).
__global__ __launch_bounds__(512, 2) void k_fused(KArgs a, int lbeg, int lend, int dosync)
{
    __shared__ __align__(16) uint4    sNe4[NCATS * 17];   // 17408 B bf16 ne, padded
    __shared__ __align__(16) float    sPart[8 * 8 * 128]; // 32 KB agg/GEMM partials
    __shared__ __align__(16) uint2    sCat[256];          // 2 KB: 8 dst cats / source
    __shared__ __align__(16) uint4    sUT[128];           // 2 KB transposed bf16 u
    __shared__ __align__(16) float    sH1[8][128];        // 4 KB
    __shared__ __align__(16) uint4    sH1T[128];          // 2 KB
    __shared__ __align__(16) float    sV[8][128];         // 4 KB   (total 64512 B)

    cg::grid_group grid = cg::this_grid();

    const int t  = threadIdx.x;
    const int b  = blockIdx.x >> 5;
    const int jg = blockIdx.x & 31;
    const int w  = t >> 6, lane = t & 63;
    const uint2* sNe2 = (const uint2*)sNe4;

    // ---------------- staging (every launch): ne + cats ----------------
    #pragma unroll 1
    for (int rr = 0; rr < 8; ++rr) {
        int r = w * 8 + rr;
        float2 em = *(const float2*)(a.emb + r * 128 + 2 * lane);
        float q = em.x * em.x + em.y * em.y;
        #pragma unroll
        for (int m = 32; m; m >>= 1) q += __shfl_xor(q, m);
        float cn = sqrtf(q);
        if (cn == 0.f) cn = 1e-8f;
        float sc = fminf(1.0f, 1.0f / cn);
        ((unsigned*)sNe4)[r * 68 + lane] = pack_bf16(em.x * sc, em.y * sc);
    }
    if (t < 256) {
        const int* p = a.ecat + t * NN + jg * 8;
        int4 c0 = *(const int4*)p;
        int4 c1 = *(const int4*)(p + 4);
        unsigned lo = (unsigned)c0.x | ((unsigned)c0.y << 8) |
                      ((unsigned)c0.z << 16) | ((unsigned)c0.w << 24);
        unsigned hi = (unsigned)c1.x | ((unsigned)c1.y << 8) |
                      ((unsigned)c1.z << 16) | ((unsigned)c1.w << 24);
        sCat[t] = make_uint2(lo, hi);
    }
    __syncthreads();

    // ---------------- phase 0: input MLP -> hA ----------------
    if (lbeg < 0) {
        for (int item = t; item < 1024; item += 512) {
            int r = item >> 7, d = item & 127;
            int row = b * NN + jg * 8 + r;
            float x0 = a.x[row * 2 + 0], x1 = a.x[row * 2 + 1];
            sV[r][d] = fmaf(x0, a.inW1[d], fmaf(x1, a.inW1[128 + d], a.inb1[d]));
        }
        __syncthreads();
        {
            float aa = sV[w][lane], cc = sV[w][lane + 64];
            float mean, rs; ln_stats(aa, cc, mean, rs);
            sH1[w][lane]      = fmaxf((aa - mean) * rs * a.ing1[lane]      + a.inbt1[lane],      0.f);
            sH1[w][lane + 64] = fmaxf((cc - mean) * rs * a.ing1[lane + 64] + a.inbt1[lane + 64], 0.f);
        }
        __syncthreads();
        {
            int dim = t & 127, q = t >> 7;
            ((unsigned*)sH1T)[dim * 4 + q] = pack_bf16(sH1[2 * q][dim], sH1[2 * q + 1][dim]);
        }
        __syncthreads();
        {   // GEMM2 (8 rows x 128), k-split 4
            const int dd = t & 127, ks = t >> 7;
            float a8[8] = {0.f,0.f,0.f,0.f,0.f,0.f,0.f,0.f};
            #pragma unroll 8
            for (int k = 0; k < 32; ++k) {
                int kk = ks * 32 + k;
                uint4 ax = sH1T[kk];
                float wv = a.inW2[kk * 128 + dd];
                a8[0] = fmaf(bf_lo(ax.x), wv, a8[0]);
                a8[1] = fmaf(bf_hi(ax.x), wv, a8[1]);
                a8[2] = fmaf(bf_lo(ax.y), wv, a8[2]);
                a8[3] = fmaf(bf_hi(ax.y), wv, a8[3]);
                a8[4] = fmaf(bf_lo(ax.z), wv, a8[4]);
                a8[5] = fmaf(bf_hi(ax.z), wv, a8[5]);
                a8[6] = fmaf(bf_lo(ax.w), wv, a8[6]);
                a8[7] = fmaf(bf_hi(ax.w), wv, a8[7]);
            }
            #pragma unroll
            for (int r = 0; r < 8; ++r) sPart[(ks * 8 + r) * 128 + dd] = a8[r];
        }
        __syncthreads();
        for (int item = t; item < 1024; item += 512) {
            int r = item >> 7, d = item & 127;
            sV[r][d] = a.inb2[d] + sPart[r * 128 + d] + sPart[(8 + r) * 128 + d] +
                       sPart[(16 + r) * 128 + d] + sPart[(24 + r) * 128 + d];
        }
        __syncthreads();
        {
            float aa = sV[w][lane], cc = sV[w][lane + 64];
            float mean, rs; ln_stats(aa, cc, mean, rs);
            int grow = b * NN + jg * 8 + w;
            a.hA[grow * HID + lane]      = (aa - mean) * rs * a.ing2[lane]      + a.inbt2[lane];
            a.hA[grow * HID + lane + 64] = (cc - mean) * rs * a.ing2[lane + 64] + a.inbt2[lane + 64];
        }
        if (dosync) grid.sync();
    }

    // ---------------- layers ----------------
    #pragma unroll 1
    for (int l = (lbeg < 0 ? 0 : lbeg); l < lend; ++l) {
        const float* h_old = (l & 1) ? a.hB : a.hA;
        float*       h_new = (l & 1) ? a.hA : a.hB;
        const float* W1  = a.cW1 + l * HID * HID;
        const float* W2  = a.cW2 + l * HID * HID;
        const float* b1  = a.cb1 + l * HID;
        const float* b2  = a.cb2 + l * HID;
        const float* g1  = a.cg1 + l * HID;
        const float* bt1 = a.cbt1 + l * HID;
        const float* g2  = a.cg2 + l * HID;
        const float* bt2 = a.cbt2 + l * HID;
        const float* lg  = a.lng + l * HID;
        const float* lb  = a.lnb + l * HID;
        const float* hb  = h_old + (size_t)b * NN * HID;
        const int isLast = (l == 3);

        // ---- aggregation: 16 src groups x 4 dims, 8 dst in regs ----
        const int dg = t & 31;
        const int ig = t >> 5;
        float acc[8][4];
        #pragma unroll
        for (int k = 0; k < 8; ++k)
            #pragma unroll
            for (int d = 0; d < 4; ++d) acc[k][d] = 0.f;

        #pragma unroll 4
        for (int n = 0; n < 16; ++n) {
            int i = ig * 16 + n;
            float4 hv = *(const float4*)(hb + i * HID + dg * 4);
            uint2 c8 = sCat[i];
            #pragma unroll
            for (int k = 0; k < 8; ++k) {
                unsigned c = ((k < 4 ? (c8.x >> (8 * k)) : (c8.y >> (8 * (k - 4)))) & 255u);
                uint2 nv = sNe2[c * 34 + dg];
                acc[k][0] += fmaxf(hv.x + bf_lo(nv.x), 0.f);
                acc[k][1] += fmaxf(hv.y + bf_hi(nv.x), 0.f);
                acc[k][2] += fmaxf(hv.z + bf_lo(nv.y), 0.f);
                acc[k][3] += fmaxf(hv.w + bf_hi(nv.y), 0.f);
            }
        }
        // merge the wave's two 16-src subgroups (lane ^ 32)
        #pragma unroll
        for (int k = 0; k < 8; ++k)
            #pragma unroll
            for (int d = 0; d < 4; ++d)
                acc[k][d] += __shfl_xor(acc[k][d], 32);
        // half-wave 0 writes dst 0..3, half-wave 1 writes dst 4..7
        {
            int kb = ((t >> 5) & 1) * 4;
            #pragma unroll
            for (int k2 = 0; k2 < 4; ++k2)
                *(float4*)&sPart[(w * 8 + kb + k2) * 128 + dg * 4] =
                    make_float4(acc[kb + k2][0], acc[kb + k2][1],
                                acc[kb + k2][2], acc[kb + k2][3]);
        }
        __syncthreads();

        // ---- combine 8 partials, u = (1+eps)*h + agg -> transposed bf16 ----
        {
            int dim = t & 127, q = t >> 7;
            const float eps1 = 1.0f + a.ceps[l];
            int r0 = 2 * q, r1 = 2 * q + 1;
            float u0 = eps1 * hb[(jg * 8 + r0) * HID + dim];
            float u1 = eps1 * hb[(jg * 8 + r1) * HID + dim];
            #pragma unroll
            for (int pg = 0; pg < 8; ++pg) {
                u0 += sPart[(pg * 8 + r0) * 128 + dim];
                u1 += sPart[(pg * 8 + r1) * 128 + dim];
            }
            ((unsigned*)sUT)[dim * 4 + q] = pack_bf16(u0, u1);
        }
        __syncthreads();

        // ---- GEMM1 ----
        {
            const int dd = t & 127, ks = t >> 7;
            float a8[8] = {0.f,0.f,0.f,0.f,0.f,0.f,0.f,0.f};
            #pragma unroll 8
            for (int k = 0; k < 32; ++k) {
                int kk = ks * 32 + k;
                uint4 ax = sUT[kk];
                float wv = W1[kk * 128 + dd];
                a8[0] = fmaf(bf_lo(ax.x), wv, a8[0]);
                a8[1] = fmaf(bf_hi(ax.x), wv, a8[1]);
                a8[2] = fmaf(bf_lo(ax.y), wv, a8[2]);
                a8[3] = fmaf(bf_hi(ax.y), wv, a8[3]);
                a8[4] = fmaf(bf_lo(ax.z), wv, a8[4]);
                a8[5] = fmaf(bf_hi(ax.z), wv, a8[5]);
                a8[6] = fmaf(bf_lo(ax.w), wv, a8[6]);
                a8[7] = fmaf(bf_hi(ax.w), wv, a8[7]);
            }
            #pragma unroll
            for (int r = 0; r < 8; ++r) sPart[(ks * 8 + r) * 128 + dd] = a8[r];
        }
        __syncthreads();
        for (int item = t; item < 1024; item += 512) {
            int r = item >> 7, d = item & 127;
            sV[r][d] = b1[d] + sPart[r * 128 + d] + sPart[(8 + r) * 128 + d] +
                       sPart[(16 + r) * 128 + d] + sPart[(24 + r) * 128 + d];
        }
        __syncthreads();

        // ---- LN1 + relu ----
        {
            float aa = sV[w][lane], cc = sV[w][lane + 64];
            float mean, rs; ln_stats(aa, cc, mean, rs);
            sH1[w][lane]      = fmaxf((aa - mean) * rs * g1[lane]      + bt1[lane],      0.f);
            sH1[w][lane + 64] = fmaxf((cc - mean) * rs * g1[lane + 64] + bt1[lane + 64], 0.f);
        }
        __syncthreads();
        {
            int dim = t & 127, q = t >> 7;
            ((unsigned*)sH1T)[dim * 4 + q] = pack_bf16(sH1[2 * q][dim], sH1[2 * q + 1][dim]);
        }
        __syncthreads();

        // ---- GEMM2 ----
        {
            const int dd = t & 127, ks = t >> 7;
            float a8[8] = {0.f,0.f,0.f,0.f,0.f,0.f,0.f,0.f};
            #pragma unroll 8
            for (int k = 0; k < 32; ++k) {
                int kk = ks * 32 + k;
                uint4 ax = sH1T[kk];
                float wv = W2[kk * 128 + dd];
                a8[0] = fmaf(bf_lo(ax.x), wv, a8[0]);
                a8[1] = fmaf(bf_hi(ax.x), wv, a8[1]);
                a8[2] = fmaf(bf_lo(ax.y), wv, a8[2]);
                a8[3] = fmaf(bf_hi(ax.y), wv, a8[3]);
                a8[4] = fmaf(bf_lo(ax.z), wv, a8[4]);
                a8[5] = fmaf(bf_hi(ax.z), wv, a8[5]);
                a8[6] = fmaf(bf_lo(ax.w), wv, a8[6]);
                a8[7] = fmaf(bf_hi(ax.w), wv, a8[7]);
            }
            #pragma unroll
            for (int r = 0; r < 8; ++r) sPart[(ks * 8 + r) * 128 + dd] = a8[r];
        }
        __syncthreads();
        for (int item = t; item < 1024; item += 512) {
            int r = item >> 7, d = item & 127;
            sV[r][d] = b2[d] + sPart[r * 128 + d] + sPart[(8 + r) * 128 + d] +
                       sPart[(16 + r) * 128 + d] + sPart[(24 + r) * 128 + d];
        }
        __syncthreads();

        // ---- LN2 -> LN3 + relu + residual -> h_new / output ----
        {
            float aa = sV[w][lane], cc = sV[w][lane + 64];
            float mean, rs; ln_stats(aa, cc, mean, rs);
            float y1 = (aa - mean) * rs * g2[lane]      + bt2[lane];
            float y2 = (cc - mean) * rs * g2[lane + 64] + bt2[lane + 64];

            float mean3, rs3; ln_stats(y1, y2, mean3, rs3);
            int row = jg * 8 + w;
            int grow = b * NN + row;
            float ho1 = hb[row * HID + lane], ho2 = hb[row * HID + lane + 64];
            float z1 = fmaxf((y1 - mean3) * rs3 * lg[lane]      + lb[lane],      0.f) + ho1;
            float z2 = fmaxf((y2 - mean3) * rs3 * lg[lane + 64] + lb[lane + 64], 0.f) + ho2;

            if (!isLast) {
                h_new[(size_t)grow * HID + lane]      = z1;
                h_new[(size_t)grow * HID + lane + 64] = z2;
            } else {
                #pragma unroll
                for (int ccx = 0; ccx < 3; ++ccx) {
                    float p = z1 * a.outW[lane * 3 + ccx] + z2 * a.outW[(lane + 64) * 3 + ccx];
                    #pragma unroll
                    for (int m = 32; m; m >>= 1) p += __shfl_xor(p, m);
                    if (lane == 0) a.dout[grow * 3 + ccx] = p + a.outb[ccx];
                }
            }
        }
        if (dosync && l < 3) grid.sync();
    }
}

// ---------------------------------------------------------------------------
extern "C" void kernel_launch(void* const* d_in, const int* in_sizes, int n_in,
                              void* d_out, int out_size, void* d_ws, size_t ws_size,
                              hipStream_t stream) {
    float* ws = (float*)d_ws;
    KArgs ka;
    ka.x     = (const float*)d_in[0];
    ka.emb   = (const float*)d_in[1];
    ka.inW1  = (const float*)d_in[2];
    ka.inb1  = (const float*)d_in[3];
    ka.ing1  = (const float*)d_in[4];
    ka.inbt1 = (const float*)d_in[5];
    ka.inW2  = (const float*)d_in[6];
    ka.inb2  = (const float*)d_in[7];
    ka.ing2  = (const float*)d_in[8];
    ka.inbt2 = (const float*)d_in[9];
    ka.cW1   = (const float*)d_in[10];
    ka.cb1   = (const float*)d_in[11];
    ka.cg1   = (const float*)d_in[12];
    ka.cbt1  = (const float*)d_in[13];
    ka.cW2   = (const float*)d_in[14];
    ka.cb2   = (const float*)d_in[15];
    ka.cg2   = (const float*)d_in[16];
    ka.cbt2  = (const float*)d_in[17];
    ka.ceps  = (const float*)d_in[18];
    ka.lng   = (const float*)d_in[19];
    ka.lnb   = (const float*)d_in[20];
    ka.outW  = (const float*)d_in[21];
    ka.outb  = (const float*)d_in[22];
    ka.ecat  = (const int*)d_in[25];
    ka.hA    = ws;
    ka.hB    = ws + BB * NN * HID;
    ka.dout  = (float*)d_out;

    // capture-safe host-side decision: can 256 blocks be co-resident?
    int nb = 0;
    hipError_t oe = hipOccupancyMaxActiveBlocksPerMultiprocessor(&nb, k_fused, 512, 0);
    bool coop_ok = (oe == hipSuccess && nb >= 1);

    if (coop_ok) {
        int lbeg = -1, lend = 4, dosync = 1;
        void* kp[] = { (void*)&ka, (void*)&lbeg, (void*)&lend, (void*)&dosync };
        hipError_t le = hipLaunchCooperativeKernel((const void*)k_fused,
                                                   dim3(256), dim3(512), kp, 0, stream);
        if (le == hipSuccess) return;
    }
    // fallback: 5 plain launches, no grid.sync needed (kernel boundaries sync)
    k_fused<<<256, 512, 0, stream>>>(ka, -1, 0, 0);
    k_fused<<<256, 512, 0, stream>>>(ka, 0, 1, 0);
    k_fused<<<256, 512, 0, stream>>>(ka, 1, 2, 0);
    k_fused<<<256, 512, 0, stream>>>(ka, 2, 3, 0);
    k_fused<<<256, 512, 0, stream>>>(ka, 3, 4, 0);
}